// Round 1
// baseline (1373.333 us; speedup 1.0000x reference)
//
#include <hip/hip_runtime.h>

#define HID 8
#define IN_DIM 3

static __device__ __forceinline__ float sigmoidf(float v) {
    return 1.0f / (1.0f + __expf(-v));
}

// ---------------------------------------------------------------------------
// Kernel 1: per-node inputnet  H = tanh(x @ W_in + b_in); feat = [H, x, pad]
// Also zeroes the H2 accumulator (d_ws is NOT re-poisoned between replays).
// feat padded to 12 floats/node so gathers are 3x float4.
// ---------------------------------------------------------------------------
__global__ void k_nodes(const float* __restrict__ x,
                        const float* __restrict__ W_in,
                        const float* __restrict__ b_in,
                        float* __restrict__ feat,
                        float* __restrict__ H2,
                        int n_nodes) {
    int i = blockIdx.x * blockDim.x + threadIdx.x;
    if (i >= n_nodes) return;
    float x0 = x[3*i+0], x1 = x[3*i+1], x2 = x[3*i+2];
    float h[8];
#pragma unroll
    for (int c = 0; c < 8; ++c) {
        float v = b_in[c] + x0 * W_in[0*8+c] + x1 * W_in[1*8+c] + x2 * W_in[2*8+c];
        h[c] = tanhf(v);
    }
    float4* fp = (float4*)(feat + (size_t)i * 12);
    fp[0] = make_float4(h[0], h[1], h[2], h[3]);
    fp[1] = make_float4(h[4], h[5], h[6], h[7]);
    fp[2] = make_float4(x0, x1, x2, 0.0f);
    float4* hp = (float4*)(H2 + (size_t)i * 8);
    hp[0] = make_float4(0.f, 0.f, 0.f, 0.f);
    hp[1] = make_float4(0.f, 0.f, 0.f, 0.f);
}

// ---------------------------------------------------------------------------
// Kernel 2: per-edge message MLP + scatter-add into H2[dst]
// e = [xi, xj - xi] (22) ; m = sig(e@W1+b1) ; m = sig(m@W2+b2) ; H2[dst] += m
// ---------------------------------------------------------------------------
__global__ void k_edges(const int* __restrict__ src,
                        const int* __restrict__ dst,
                        const float* __restrict__ feat,
                        const float* __restrict__ W1,
                        const float* __restrict__ b1,
                        const float* __restrict__ W2,
                        const float* __restrict__ b2,
                        float* __restrict__ H2,
                        int n_edges) {
    __shared__ float sW1[22 * 8];
    __shared__ float sW2[8 * 8];
    __shared__ float sb1[8];
    __shared__ float sb2[8];
    for (int t = threadIdx.x; t < 22 * 8; t += blockDim.x) sW1[t] = W1[t];
    for (int t = threadIdx.x; t < 8 * 8; t += blockDim.x)  sW2[t] = W2[t];
    if (threadIdx.x < 8) { sb1[threadIdx.x] = b1[threadIdx.x]; sb2[threadIdx.x] = b2[threadIdx.x]; }
    __syncthreads();

    int e = blockIdx.x * blockDim.x + threadIdx.x;
    if (e >= n_edges) return;
    int j = src[e];   // source
    int i = dst[e];   // target

    const float4* fi = (const float4*)(feat + (size_t)i * 12);
    const float4* fj = (const float4*)(feat + (size_t)j * 12);
    float4 i0 = fi[0], i1 = fi[1], i2 = fi[2];
    float4 j0 = fj[0], j1 = fj[1], j2 = fj[2];

    float xi[11] = { i0.x, i0.y, i0.z, i0.w, i1.x, i1.y, i1.z, i1.w, i2.x, i2.y, i2.z };
    float xj[11] = { j0.x, j0.y, j0.z, j0.w, j1.x, j1.y, j1.z, j1.w, j2.x, j2.y, j2.z };
    float dd[11];
#pragma unroll
    for (int k = 0; k < 11; ++k) dd[k] = xj[k] - xi[k];

    float m[8];
#pragma unroll
    for (int h = 0; h < 8; ++h) {
        float v = sb1[h];
#pragma unroll
        for (int k = 0; k < 11; ++k) v += xi[k] * sW1[k * 8 + h];
#pragma unroll
        for (int k = 0; k < 11; ++k) v += dd[k] * sW1[(11 + k) * 8 + h];
        m[h] = sigmoidf(v);
    }
    float m2[8];
#pragma unroll
    for (int h = 0; h < 8; ++h) {
        float v = sb2[h];
#pragma unroll
        for (int k = 0; k < 8; ++k) v += m[k] * sW2[k * 8 + h];
        m2[h] = sigmoidf(v);
    }

    float* hp = H2 + (size_t)i * 8;
#pragma unroll
    for (int h = 0; h < 8; ++h) atomicAdd(hp + h, m2[h]);
}

// ---------------------------------------------------------------------------
// Kernel 3: per-edge output  ef = [feat2[src], feat2[dst]] (22) @ W_e -> sigmoid
// feat2[n] = [H2[n][0..7], x[n][0..2]]
// ---------------------------------------------------------------------------
__global__ void k_out(const int* __restrict__ src,
                      const int* __restrict__ dst,
                      const float* __restrict__ H2,
                      const float* __restrict__ x,
                      const float* __restrict__ W_e,
                      const float* __restrict__ b_e,
                      float* __restrict__ out,
                      int n_edges) {
    __shared__ float sW[22];
    __shared__ float sb;
    if (threadIdx.x < 22) sW[threadIdx.x] = W_e[threadIdx.x];
    if (threadIdx.x == 0) sb = b_e[0];
    __syncthreads();

    int e = blockIdx.x * blockDim.x + threadIdx.x;
    if (e >= n_edges) return;
    int j = src[e];   // source -> first 11 weights
    int i = dst[e];   // target -> last 11 weights

    const float4* hj = (const float4*)(H2 + (size_t)j * 8);
    const float4* hi = (const float4*)(H2 + (size_t)i * 8);
    float4 a0 = hj[0], a1 = hj[1];
    float4 c0 = hi[0], c1 = hi[1];

    float acc = sb;
    acc += a0.x * sW[0] + a0.y * sW[1] + a0.z * sW[2] + a0.w * sW[3];
    acc += a1.x * sW[4] + a1.y * sW[5] + a1.z * sW[6] + a1.w * sW[7];
    acc += x[3 * (size_t)j + 0] * sW[8] + x[3 * (size_t)j + 1] * sW[9] + x[3 * (size_t)j + 2] * sW[10];
    acc += c0.x * sW[11] + c0.y * sW[12] + c0.z * sW[13] + c0.w * sW[14];
    acc += c1.x * sW[15] + c1.y * sW[16] + c1.z * sW[17] + c1.w * sW[18];
    acc += x[3 * (size_t)i + 0] * sW[19] + x[3 * (size_t)i + 1] * sW[20] + x[3 * (size_t)i + 2] * sW[21];

    out[e] = sigmoidf(acc);
}

// ---------------------------------------------------------------------------
extern "C" void kernel_launch(void* const* d_in, const int* in_sizes, int n_in,
                              void* d_out, int out_size, void* d_ws, size_t ws_size,
                              hipStream_t stream) {
    const float* x    = (const float*)d_in[0];
    const int*   ei   = (const int*)d_in[1];
    const float* W_in = (const float*)d_in[2];
    const float* b_in = (const float*)d_in[3];
    const float* W1   = (const float*)d_in[4];
    const float* b1   = (const float*)d_in[5];
    const float* W2   = (const float*)d_in[6];
    const float* b2   = (const float*)d_in[7];
    const float* W_e  = (const float*)d_in[8];
    const float* b_e  = (const float*)d_in[9];

    const int n_nodes = in_sizes[0] / 3;
    const int n_edges = in_sizes[1] / 2;
    const int* src = ei;             // edge_index[0]
    const int* dst = ei + n_edges;   // edge_index[1]

    float* feat = (float*)d_ws;                         // [n_nodes][12]
    float* H2   = feat + (size_t)n_nodes * 12;          // [n_nodes][8]
    float* out  = (float*)d_out;

    const int B = 256;
    k_nodes<<<(n_nodes + B - 1) / B, B, 0, stream>>>(x, W_in, b_in, feat, H2, n_nodes);
    k_edges<<<(n_edges + B - 1) / B, B, 0, stream>>>(src, dst, feat, W1, b1, W2, b2, H2, n_edges);
    k_out  <<<(n_edges + B - 1) / B, B, 0, stream>>>(src, dst, H2, x, W_e, b_e, out, n_edges);
}

// Round 2
// 385.362 us; speedup vs baseline: 3.5637x; 3.5637x over previous
//
#include <hip/hip_runtime.h>

#define TPB 256

static __device__ __forceinline__ float sigmoidf(float v) {
    return 1.0f / (1.0f + __expf(-v));
}

// ===========================================================================
// FAST PATH: per-call counting-sort CSR by dst, non-atomic message stores,
// coalesced segment reduce folded into the final W_e dot.
// ===========================================================================

// K1: per-node inputnet: feat = [tanh(x@W_in+b_in), x, pad]; zero counts.
__global__ void k_nodes2(const float* __restrict__ x,
                         const float* __restrict__ W_in,
                         const float* __restrict__ b_in,
                         float* __restrict__ feat,
                         int* __restrict__ counts,
                         int n_nodes) {
    int i = blockIdx.x * blockDim.x + threadIdx.x;
    if (i >= n_nodes) return;
    counts[i] = 0;
    float x0 = x[3*i+0], x1 = x[3*i+1], x2 = x[3*i+2];
    float h[8];
#pragma unroll
    for (int c = 0; c < 8; ++c) {
        float v = b_in[c] + x0 * W_in[0*8+c] + x1 * W_in[1*8+c] + x2 * W_in[2*8+c];
        h[c] = tanhf(v);
    }
    float4* fp = (float4*)(feat + (size_t)i * 12);
    fp[0] = make_float4(h[0], h[1], h[2], h[3]);
    fp[1] = make_float4(h[4], h[5], h[6], h[7]);
    fp[2] = make_float4(x0, x1, x2, 0.0f);
}

// K2: histogram of dst
__global__ void k_hist(const int* __restrict__ dst, int* __restrict__ counts,
                       int n_edges) {
    int e = blockIdx.x * blockDim.x + threadIdx.x;
    if (e < n_edges) atomicAdd(&counts[dst[e]], 1);
}

// K3a: per-1024-chunk sums of counts
__global__ void k_scan_a(const int* __restrict__ counts, int* __restrict__ chunkSum,
                         int n) {
    __shared__ int s[TPB];
    int t = threadIdx.x;
    int base = blockIdx.x * (TPB * 4) + t * 4;
    int v = 0;
#pragma unroll
    for (int k = 0; k < 4; ++k) { int idx = base + k; if (idx < n) v += counts[idx]; }
    s[t] = v; __syncthreads();
    for (int o = TPB / 2; o > 0; o >>= 1) { if (t < o) s[t] += s[t + o]; __syncthreads(); }
    if (t == 0) chunkSum[blockIdx.x] = s[0];
}

// K3b: serial exclusive scan of chunk sums (~98 elements)
__global__ void k_scan_b(const int* __restrict__ chunkSum, int* __restrict__ chunkOff,
                         int nch) {
    if (threadIdx.x == 0 && blockIdx.x == 0) {
        int acc = 0;
        for (int i = 0; i < nch; ++i) { chunkOff[i] = acc; acc += chunkSum[i]; }
    }
}

// K3c: per-chunk exclusive scan + chunk offset -> offsets, cursor
__global__ void k_scan_c(const int* __restrict__ counts, const int* __restrict__ chunkOff,
                         int* __restrict__ offsets, int* __restrict__ cursor,
                         int n, int total_edges) {
    __shared__ int s[TPB];
    int t = threadIdx.x;
    int base = blockIdx.x * (TPB * 4) + t * 4;
    int c[4]; int tsum = 0;
#pragma unroll
    for (int k = 0; k < 4; ++k) { int idx = base + k; c[k] = (idx < n) ? counts[idx] : 0; tsum += c[k]; }
    s[t] = tsum; __syncthreads();
    // inclusive Hillis-Steele scan over 256 thread partials
    for (int o = 1; o < TPB; o <<= 1) {
        int v = (t >= o) ? s[t - o] : 0;
        __syncthreads();
        s[t] += v;
        __syncthreads();
    }
    int excl = s[t] - tsum;
    int g = chunkOff[blockIdx.x] + excl;
#pragma unroll
    for (int k = 0; k < 4; ++k) {
        int idx = base + k;
        if (idx < n) { offsets[idx] = g; cursor[idx] = g; g += c[k]; }
    }
    if (blockIdx.x == 0 && t == 0) offsets[n] = total_edges;
}

// K4: per-edge message MLP; place message in its dst segment (1 int atomic).
__global__ void k_msg(const int* __restrict__ src,
                      const int* __restrict__ dst,
                      const float* __restrict__ feat,
                      const float* __restrict__ W1,
                      const float* __restrict__ b1,
                      const float* __restrict__ W2,
                      const float* __restrict__ b2,
                      int* __restrict__ cursor,
                      float* __restrict__ msg,
                      int n_edges) {
    __shared__ float sW1[22 * 8];
    __shared__ float sW2[8 * 8];
    __shared__ float sb1[8];
    __shared__ float sb2[8];
    for (int t = threadIdx.x; t < 22 * 8; t += blockDim.x) sW1[t] = W1[t];
    for (int t = threadIdx.x; t < 8 * 8; t += blockDim.x)  sW2[t] = W2[t];
    if (threadIdx.x < 8) { sb1[threadIdx.x] = b1[threadIdx.x]; sb2[threadIdx.x] = b2[threadIdx.x]; }
    __syncthreads();

    int e = blockIdx.x * blockDim.x + threadIdx.x;
    if (e >= n_edges) return;
    int j = src[e];   // source
    int i = dst[e];   // target

    const float4* fi = (const float4*)(feat + (size_t)i * 12);
    const float4* fj = (const float4*)(feat + (size_t)j * 12);
    float4 i0 = fi[0], i1 = fi[1], i2 = fi[2];
    float4 j0 = fj[0], j1 = fj[1], j2 = fj[2];

    float xi[11] = { i0.x, i0.y, i0.z, i0.w, i1.x, i1.y, i1.z, i1.w, i2.x, i2.y, i2.z };
    float xj[11] = { j0.x, j0.y, j0.z, j0.w, j1.x, j1.y, j1.z, j1.w, j2.x, j2.y, j2.z };
    float dd[11];
#pragma unroll
    for (int k = 0; k < 11; ++k) dd[k] = xj[k] - xi[k];

    float m[8];
#pragma unroll
    for (int h = 0; h < 8; ++h) {
        float v = sb1[h];
#pragma unroll
        for (int k = 0; k < 11; ++k) v += xi[k] * sW1[k * 8 + h];
#pragma unroll
        for (int k = 0; k < 11; ++k) v += dd[k] * sW1[(11 + k) * 8 + h];
        m[h] = sigmoidf(v);
    }
    float m2[8];
#pragma unroll
    for (int h = 0; h < 8; ++h) {
        float v = sb2[h];
#pragma unroll
        for (int k = 0; k < 8; ++k) v += m[k] * sW2[k * 8 + h];
        m2[h] = sigmoidf(v);
    }

    int pos = atomicAdd(&cursor[i], 1);
    float4* mp = (float4*)(msg + (size_t)pos * 8);
    mp[0] = make_float4(m2[0], m2[1], m2[2], m2[3]);
    mp[1] = make_float4(m2[4], m2[5], m2[6], m2[7]);
}

// K5: per-node segment reduce of messages, folded directly into the two
// scalar projections a[n]=W_e[0:11]·feat2[n], c[n]=W_e[11:22]·feat2[n].
// 8 lanes per node; lane l owns channel l.
__global__ void k_reduce_ac(const int* __restrict__ offsets,
                            const float* __restrict__ msg,
                            const float* __restrict__ x,
                            const float* __restrict__ W_e,
                            float* __restrict__ ac,
                            int n_nodes) {
    int idx = blockIdx.x * blockDim.x + threadIdx.x;
    int node = idx >> 3;
    int lane = idx & 7;
    if (node >= n_nodes) return;
    int beg = offsets[node], end = offsets[node + 1];
    float s = 0.0f;
    for (int r = beg; r < end; ++r) s += msg[(size_t)r * 8 + lane];
    float pa = s * W_e[lane];
    float pc = s * W_e[11 + lane];
#pragma unroll
    for (int o = 4; o > 0; o >>= 1) {
        pa += __shfl_xor(pa, o, 8);
        pc += __shfl_xor(pc, o, 8);
    }
    if (lane == 0) {
        float x0 = x[3*node+0], x1 = x[3*node+1], x2 = x[3*node+2];
        pa += x0 * W_e[8]  + x1 * W_e[9]  + x2 * W_e[10];
        pc += x0 * W_e[19] + x1 * W_e[20] + x2 * W_e[21];
        ac[2*node+0] = pa;
        ac[2*node+1] = pc;
    }
}

// K6: out[e] = sigmoid(a[src] + c[dst] + b_e)
__global__ void k_out2(const int* __restrict__ src,
                       const int* __restrict__ dst,
                       const float* __restrict__ ac,
                       const float* __restrict__ b_e,
                       float* __restrict__ out,
                       int n_edges) {
    int e = blockIdx.x * blockDim.x + threadIdx.x;
    if (e >= n_edges) return;
    out[e] = sigmoidf(ac[2*src[e]] + ac[2*dst[e] + 1] + b_e[0]);
}

// ===========================================================================
// FALLBACK PATH (round-1, proven): used only if ws_size is too small.
// ===========================================================================
__global__ void k_nodes(const float* __restrict__ x, const float* __restrict__ W_in,
                        const float* __restrict__ b_in, float* __restrict__ feat,
                        float* __restrict__ H2, int n_nodes) {
    int i = blockIdx.x * blockDim.x + threadIdx.x;
    if (i >= n_nodes) return;
    float x0 = x[3*i+0], x1 = x[3*i+1], x2 = x[3*i+2];
    float h[8];
#pragma unroll
    for (int c = 0; c < 8; ++c)
        h[c] = tanhf(b_in[c] + x0*W_in[c] + x1*W_in[8+c] + x2*W_in[16+c]);
    float4* fp = (float4*)(feat + (size_t)i * 12);
    fp[0] = make_float4(h[0], h[1], h[2], h[3]);
    fp[1] = make_float4(h[4], h[5], h[6], h[7]);
    fp[2] = make_float4(x0, x1, x2, 0.0f);
    float4* hp = (float4*)(H2 + (size_t)i * 8);
    hp[0] = make_float4(0,0,0,0); hp[1] = make_float4(0,0,0,0);
}

__global__ void k_edges(const int* __restrict__ src, const int* __restrict__ dst,
                        const float* __restrict__ feat, const float* __restrict__ W1,
                        const float* __restrict__ b1, const float* __restrict__ W2,
                        const float* __restrict__ b2, float* __restrict__ H2,
                        int n_edges) {
    __shared__ float sW1[176], sW2[64], sb1[8], sb2[8];
    for (int t = threadIdx.x; t < 176; t += blockDim.x) sW1[t] = W1[t];
    for (int t = threadIdx.x; t < 64; t += blockDim.x)  sW2[t] = W2[t];
    if (threadIdx.x < 8) { sb1[threadIdx.x] = b1[threadIdx.x]; sb2[threadIdx.x] = b2[threadIdx.x]; }
    __syncthreads();
    int e = blockIdx.x * blockDim.x + threadIdx.x;
    if (e >= n_edges) return;
    int j = src[e], i = dst[e];
    const float4* fi = (const float4*)(feat + (size_t)i * 12);
    const float4* fj = (const float4*)(feat + (size_t)j * 12);
    float4 i0 = fi[0], i1 = fi[1], i2 = fi[2];
    float4 j0 = fj[0], j1 = fj[1], j2 = fj[2];
    float xi[11] = { i0.x,i0.y,i0.z,i0.w,i1.x,i1.y,i1.z,i1.w,i2.x,i2.y,i2.z };
    float xj[11] = { j0.x,j0.y,j0.z,j0.w,j1.x,j1.y,j1.z,j1.w,j2.x,j2.y,j2.z };
    float dd[11];
#pragma unroll
    for (int k = 0; k < 11; ++k) dd[k] = xj[k] - xi[k];
    float m[8];
#pragma unroll
    for (int h = 0; h < 8; ++h) {
        float v = sb1[h];
#pragma unroll
        for (int k = 0; k < 11; ++k) v += xi[k] * sW1[k*8+h];
#pragma unroll
        for (int k = 0; k < 11; ++k) v += dd[k] * sW1[(11+k)*8+h];
        m[h] = sigmoidf(v);
    }
    float m2[8];
#pragma unroll
    for (int h = 0; h < 8; ++h) {
        float v = sb2[h];
#pragma unroll
        for (int k = 0; k < 8; ++k) v += m[k] * sW2[k*8+h];
        m2[h] = sigmoidf(v);
    }
    float* hp = H2 + (size_t)i * 8;
#pragma unroll
    for (int h = 0; h < 8; ++h) atomicAdd(hp + h, m2[h]);
}

__global__ void k_out(const int* __restrict__ src, const int* __restrict__ dst,
                      const float* __restrict__ H2, const float* __restrict__ x,
                      const float* __restrict__ W_e, const float* __restrict__ b_e,
                      float* __restrict__ out, int n_edges) {
    __shared__ float sW[22]; __shared__ float sb;
    if (threadIdx.x < 22) sW[threadIdx.x] = W_e[threadIdx.x];
    if (threadIdx.x == 0) sb = b_e[0];
    __syncthreads();
    int e = blockIdx.x * blockDim.x + threadIdx.x;
    if (e >= n_edges) return;
    int j = src[e], i = dst[e];
    const float4* hj = (const float4*)(H2 + (size_t)j * 8);
    const float4* hi = (const float4*)(H2 + (size_t)i * 8);
    float4 a0 = hj[0], a1 = hj[1], c0 = hi[0], c1 = hi[1];
    float acc = sb;
    acc += a0.x*sW[0] + a0.y*sW[1] + a0.z*sW[2] + a0.w*sW[3];
    acc += a1.x*sW[4] + a1.y*sW[5] + a1.z*sW[6] + a1.w*sW[7];
    acc += x[3*(size_t)j+0]*sW[8] + x[3*(size_t)j+1]*sW[9] + x[3*(size_t)j+2]*sW[10];
    acc += c0.x*sW[11] + c0.y*sW[12] + c0.z*sW[13] + c0.w*sW[14];
    acc += c1.x*sW[15] + c1.y*sW[16] + c1.z*sW[17] + c1.w*sW[18];
    acc += x[3*(size_t)i+0]*sW[19] + x[3*(size_t)i+1]*sW[20] + x[3*(size_t)i+2]*sW[21];
    out[e] = sigmoidf(acc);
}

// ===========================================================================
extern "C" void kernel_launch(void* const* d_in, const int* in_sizes, int n_in,
                              void* d_out, int out_size, void* d_ws, size_t ws_size,
                              hipStream_t stream) {
    const float* x    = (const float*)d_in[0];
    const int*   ei   = (const int*)d_in[1];
    const float* W_in = (const float*)d_in[2];
    const float* b_in = (const float*)d_in[3];
    const float* W1   = (const float*)d_in[4];
    const float* b1   = (const float*)d_in[5];
    const float* W2   = (const float*)d_in[6];
    const float* b2   = (const float*)d_in[7];
    const float* W_e  = (const float*)d_in[8];
    const float* b_e  = (const float*)d_in[9];

    const int n_nodes = in_sizes[0] / 3;
    const int n_edges = in_sizes[1] / 2;
    const int* src = ei;
    const int* dst = ei + n_edges;
    float* out = (float*)d_out;

    const int B = TPB;
    const int nch = (n_nodes + 1023) / 1024;

    // ws layout for fast path (256B-aligned regions)
    size_t off = 0;
    auto carve = [&](size_t bytes) { size_t o = off; off += (bytes + 255) & ~(size_t)255; return o; };
    char* ws = (char*)d_ws;
    size_t o_feat    = carve((size_t)n_nodes * 12 * 4);
    size_t o_ac      = carve((size_t)n_nodes * 2 * 4);
    size_t o_counts  = carve((size_t)n_nodes * 4);
    size_t o_offsets = carve(((size_t)n_nodes + 1) * 4);
    size_t o_cursor  = carve((size_t)n_nodes * 4);
    size_t o_csum    = carve((size_t)nch * 4);
    size_t o_coff    = carve((size_t)nch * 4);
    size_t o_msg     = carve((size_t)n_edges * 8 * 4);
    bool fast = (off <= ws_size);

    if (fast) {
        float* feat    = (float*)(ws + o_feat);
        float* ac      = (float*)(ws + o_ac);
        int*   counts  = (int*)(ws + o_counts);
        int*   offsets = (int*)(ws + o_offsets);
        int*   cursor  = (int*)(ws + o_cursor);
        int*   csum    = (int*)(ws + o_csum);
        int*   coff    = (int*)(ws + o_coff);
        float* msg     = (float*)(ws + o_msg);

        k_nodes2<<<(n_nodes + B - 1) / B, B, 0, stream>>>(x, W_in, b_in, feat, counts, n_nodes);
        k_hist  <<<(n_edges + B - 1) / B, B, 0, stream>>>(dst, counts, n_edges);
        k_scan_a<<<nch, B, 0, stream>>>(counts, csum, n_nodes);
        k_scan_b<<<1, 64, 0, stream>>>(csum, coff, nch);
        k_scan_c<<<nch, B, 0, stream>>>(counts, coff, offsets, cursor, n_nodes, n_edges);
        k_msg   <<<(n_edges + B - 1) / B, B, 0, stream>>>(src, dst, feat, W1, b1, W2, b2,
                                                          cursor, msg, n_edges);
        k_reduce_ac<<<((n_nodes * 8) + B - 1) / B, B, 0, stream>>>(offsets, msg, x, W_e, ac, n_nodes);
        k_out2  <<<(n_edges + B - 1) / B, B, 0, stream>>>(src, dst, ac, b_e, out, n_edges);
    } else {
        float* feat = (float*)d_ws;
        float* H2   = feat + (size_t)n_nodes * 12;
        k_nodes<<<(n_nodes + B - 1) / B, B, 0, stream>>>(x, W_in, b_in, feat, H2, n_nodes);
        k_edges<<<(n_edges + B - 1) / B, B, 0, stream>>>(src, dst, feat, W1, b1, W2, b2, H2, n_edges);
        k_out  <<<(n_edges + B - 1) / B, B, 0, stream>>>(src, dst, H2, x, W_e, b_e, out, n_edges);
    }
}

// Round 3
// 230.687 us; speedup vs baseline: 5.9532x; 1.6705x over previous
//
#include <hip/hip_runtime.h>

#define TPB   256
#define BSH   7              // bucket = dst >> 7  (128 nodes / bucket)
#define BW    128
#define EPB   4096           // edges per partition block (256 thr x 16)
#define MAXNB 1024

static __device__ __forceinline__ float sigmoidf(float v) {
    return 1.0f / (1.0f + __expf(-v));
}

// ===========================================================================
// K1: per-node inputnet: feat[n] = [tanh(x@W_in+b_in) (8), x (3), pad] stride 12
// ===========================================================================
__global__ void k_feat(const float* __restrict__ x,
                       const float* __restrict__ W_in,
                       const float* __restrict__ b_in,
                       float* __restrict__ feat, int n_nodes) {
    int i = blockIdx.x * blockDim.x + threadIdx.x;
    if (i >= n_nodes) return;
    float x0 = x[3*i+0], x1 = x[3*i+1], x2 = x[3*i+2];
    float h[8];
#pragma unroll
    for (int c = 0; c < 8; ++c)
        h[c] = tanhf(b_in[c] + x0*W_in[c] + x1*W_in[8+c] + x2*W_in[16+c]);
    float4* fp = (float4*)(feat + (size_t)i * 12);
    fp[0] = make_float4(h[0], h[1], h[2], h[3]);
    fp[1] = make_float4(h[4], h[5], h[6], h[7]);
    fp[2] = make_float4(x0, x1, x2, 0.0f);
}

// ===========================================================================
// K2: per-block bucket histogram (LDS only), hist[blk][b] row-major coalesced
// ===========================================================================
__global__ void k_hist2(const int* __restrict__ dst, int* __restrict__ hist,
                        int n_edges, int NB) {
    __shared__ int cnt[MAXNB];
    for (int b = threadIdx.x; b < NB; b += blockDim.x) cnt[b] = 0;
    __syncthreads();
    int e0 = blockIdx.x * EPB;
#pragma unroll
    for (int k = 0; k < EPB / TPB; ++k) {
        int e = e0 + k * TPB + threadIdx.x;
        if (e < n_edges) atomicAdd(&cnt[dst[e] >> BSH], 1);
    }
    __syncthreads();
    for (int b = threadIdx.x; b < NB; b += blockDim.x)
        hist[(size_t)blockIdx.x * NB + b] = cnt[b];
}

// ===========================================================================
// K3: per-bucket (column) exclusive scan over blocks; hist <- rel offsets,
//     totals[b] = bucket size. One WG per bucket; matrix is L2-resident.
// ===========================================================================
__global__ void k_scan_cols(int* __restrict__ hist, int* __restrict__ totals,
                            int NB, int NBLK) {
    __shared__ int s[TPB];
    int b = blockIdx.x, t = threadIdx.x;
    int carry = 0;
    for (int q = 0; q < NBLK; q += TPB) {
        int blk = q + t;
        int v = (blk < NBLK) ? hist[(size_t)blk * NB + b] : 0;
        __syncthreads();               // protect s reuse from previous chunk
        s[t] = v; __syncthreads();
        for (int o = 1; o < TPB; o <<= 1) {
            int u = (t >= o) ? s[t - o] : 0;
            __syncthreads();
            s[t] += u;
            __syncthreads();
        }
        int incl = s[t];
        int tot  = s[TPB - 1];
        if (blk < NBLK) hist[(size_t)blk * NB + b] = carry + incl - v;  // exclusive
        carry += tot;
    }
    if (t == 0) totals[b] = carry;
}

// K3b: exclusive scan of totals -> base[0..NB], base[NB]=n_edges. 1 WG, 1024 thr.
__global__ void k_base(const int* __restrict__ totals, int* __restrict__ base,
                       int NB, int n_edges) {
    __shared__ int s[MAXNB];
    int t = threadIdx.x;
    int v = (t < NB) ? totals[t] : 0;
    s[t] = v; __syncthreads();
    for (int o = 1; o < MAXNB; o <<= 1) {
        int u = (t >= o) ? s[t - o] : 0;
        __syncthreads();
        s[t] += u;
        __syncthreads();
    }
    if (t < NB) base[t] = s[t] - v;
    if (t == 0) base[NB] = n_edges;
}

// ===========================================================================
// K4: scatter pass — block preloads its row of offsets (+base) into LDS,
//     per-edge LDS cursor atomic, write packed (src<<7 | dst&127).
// ===========================================================================
__global__ void k_scatter(const int* __restrict__ src, const int* __restrict__ dst,
                          const int* __restrict__ hist, const int* __restrict__ base,
                          int* __restrict__ sorted, int n_edges, int NB) {
    __shared__ int offl[MAXNB];
    for (int b = threadIdx.x; b < NB; b += blockDim.x)
        offl[b] = base[b] + hist[(size_t)blockIdx.x * NB + b];
    __syncthreads();
    int e0 = blockIdx.x * EPB;
#pragma unroll
    for (int k = 0; k < EPB / TPB; ++k) {
        int e = e0 + k * TPB + threadIdx.x;
        if (e < n_edges) {
            int d = dst[e];
            int b = d >> BSH;
            int pos = atomicAdd(&offl[b], 1);
            sorted[pos] = (src[e] << BSH) | (d & (BW - 1));
        }
    }
}

// ===========================================================================
// K5: fused per-bucket MLP + reduction. One WG per bucket of 128 nodes.
//     xi staged in LDS (stride 13), messages collapsed to (pa,pc) scalars,
//     accumulated via LDS float atomics. Writes ac[2n],ac[2n+1].
// ===========================================================================
__launch_bounds__(TPB)
__global__ void k_bucket(const int* __restrict__ sorted, const int* __restrict__ base,
                         const float* __restrict__ feat,
                         const float* __restrict__ W1, const float* __restrict__ b1,
                         const float* __restrict__ W2, const float* __restrict__ b2,
                         const float* __restrict__ W_e,
                         float* __restrict__ ac, int n_nodes) {
    __shared__ float sfeat[BW * 13];
    __shared__ float sa[BW], sc[BW];
    __shared__ float sW1[176], sW2[64], sb1[8], sb2[8], sWe[22];
    int t = threadIdx.x, b = blockIdx.x;

    for (int i = t; i < 176; i += TPB) sW1[i] = W1[i];
    for (int i = t; i < 64;  i += TPB) sW2[i] = W2[i];
    if (t < 8)  { sb1[t] = b1[t]; sb2[t] = b2[t]; }
    if (t < 22) sWe[t] = W_e[t];
    if (t < BW) { sa[t] = 0.0f; sc[t] = 0.0f; }

    int nb0 = b * BW;
    int nn = min(BW, n_nodes - nb0);
    for (int i = t; i < nn * 12; i += TPB) {
        int r = i / 12, cc = i - r * 12;
        sfeat[r * 13 + cc] = feat[(size_t)nb0 * 12 + i];
    }
    __syncthreads();

    int beg = base[b], end = base[b + 1];
    for (int e = beg + t; e < end; e += TPB) {
        int p  = sorted[e];
        int s  = p >> BSH;
        int dl = p & (BW - 1);

        const float4* fj = (const float4*)(feat + (size_t)s * 12);
        float4 j0 = fj[0], j1 = fj[1], j2 = fj[2];
        float xj[11] = { j0.x, j0.y, j0.z, j0.w, j1.x, j1.y, j1.z, j1.w, j2.x, j2.y, j2.z };
        float xi[11];
#pragma unroll
        for (int k = 0; k < 11; ++k) xi[k] = sfeat[dl * 13 + k];
        float dd[11];
#pragma unroll
        for (int k = 0; k < 11; ++k) dd[k] = xj[k] - xi[k];

        float m[8];
#pragma unroll
        for (int h = 0; h < 8; ++h) {
            float v = sb1[h];
#pragma unroll
            for (int k = 0; k < 11; ++k) v += xi[k] * sW1[k * 8 + h];
#pragma unroll
            for (int k = 0; k < 11; ++k) v += dd[k] * sW1[(11 + k) * 8 + h];
            m[h] = sigmoidf(v);
        }
        float pa = 0.0f, pc = 0.0f;
#pragma unroll
        for (int h = 0; h < 8; ++h) {
            float v = sb2[h];
#pragma unroll
            for (int k = 0; k < 8; ++k) v += m[k] * sW2[k * 8 + h];
            float mm = sigmoidf(v);
            pa += mm * sWe[h];
            pc += mm * sWe[11 + h];
        }
        atomicAdd(&sa[dl], pa);
        atomicAdd(&sc[dl], pc);
    }
    __syncthreads();

    if (t < nn) {
        float xx0 = sfeat[t * 13 + 8], xx1 = sfeat[t * 13 + 9], xx2 = sfeat[t * 13 + 10];
        int n = nb0 + t;
        ac[2 * n + 0] = sa[t] + xx0 * sWe[8]  + xx1 * sWe[9]  + xx2 * sWe[10];
        ac[2 * n + 1] = sc[t] + xx0 * sWe[19] + xx1 * sWe[20] + xx2 * sWe[21];
    }
}

// ===========================================================================
// K6: out[e] = sigmoid(a[src] + c[dst] + b_e)
// ===========================================================================
__global__ void k_out2(const int* __restrict__ src, const int* __restrict__ dst,
                       const float* __restrict__ ac, const float* __restrict__ b_e,
                       float* __restrict__ out, int n_edges) {
    int e = blockIdx.x * blockDim.x + threadIdx.x;
    if (e >= n_edges) return;
    out[e] = sigmoidf(ac[2 * src[e]] + ac[2 * dst[e] + 1] + b_e[0]);
}

// ===========================================================================
// FALLBACK (round-1, proven) — only if NB > MAXNB or ws too small.
// ===========================================================================
__global__ void k_nodes(const float* __restrict__ x, const float* __restrict__ W_in,
                        const float* __restrict__ b_in, float* __restrict__ feat,
                        float* __restrict__ H2, int n_nodes) {
    int i = blockIdx.x * blockDim.x + threadIdx.x;
    if (i >= n_nodes) return;
    float x0 = x[3*i], x1 = x[3*i+1], x2 = x[3*i+2];
    float h[8];
#pragma unroll
    for (int c = 0; c < 8; ++c)
        h[c] = tanhf(b_in[c] + x0*W_in[c] + x1*W_in[8+c] + x2*W_in[16+c]);
    float4* fp = (float4*)(feat + (size_t)i * 12);
    fp[0] = make_float4(h[0],h[1],h[2],h[3]);
    fp[1] = make_float4(h[4],h[5],h[6],h[7]);
    fp[2] = make_float4(x0,x1,x2,0.0f);
    float4* hp = (float4*)(H2 + (size_t)i * 8);
    hp[0] = make_float4(0,0,0,0); hp[1] = make_float4(0,0,0,0);
}

__global__ void k_edges(const int* __restrict__ src, const int* __restrict__ dst,
                        const float* __restrict__ feat, const float* __restrict__ W1,
                        const float* __restrict__ b1, const float* __restrict__ W2,
                        const float* __restrict__ b2, float* __restrict__ H2,
                        int n_edges) {
    __shared__ float sW1[176], sW2[64], sb1[8], sb2[8];
    for (int t = threadIdx.x; t < 176; t += blockDim.x) sW1[t] = W1[t];
    for (int t = threadIdx.x; t < 64;  t += blockDim.x) sW2[t] = W2[t];
    if (threadIdx.x < 8) { sb1[threadIdx.x]=b1[threadIdx.x]; sb2[threadIdx.x]=b2[threadIdx.x]; }
    __syncthreads();
    int e = blockIdx.x * blockDim.x + threadIdx.x;
    if (e >= n_edges) return;
    int j = src[e], i = dst[e];
    const float4* fi = (const float4*)(feat + (size_t)i * 12);
    const float4* fj = (const float4*)(feat + (size_t)j * 12);
    float4 i0=fi[0],i1=fi[1],i2=fi[2],j0=fj[0],j1=fj[1],j2=fj[2];
    float xi[11]={i0.x,i0.y,i0.z,i0.w,i1.x,i1.y,i1.z,i1.w,i2.x,i2.y,i2.z};
    float xj[11]={j0.x,j0.y,j0.z,j0.w,j1.x,j1.y,j1.z,j1.w,j2.x,j2.y,j2.z};
    float dd[11];
#pragma unroll
    for (int k = 0; k < 11; ++k) dd[k]=xj[k]-xi[k];
    float m[8];
#pragma unroll
    for (int h = 0; h < 8; ++h) {
        float v = sb1[h];
#pragma unroll
        for (int k = 0; k < 11; ++k) v += xi[k]*sW1[k*8+h];
#pragma unroll
        for (int k = 0; k < 11; ++k) v += dd[k]*sW1[(11+k)*8+h];
        m[h] = sigmoidf(v);
    }
    float m2[8];
#pragma unroll
    for (int h = 0; h < 8; ++h) {
        float v = sb2[h];
#pragma unroll
        for (int k = 0; k < 8; ++k) v += m[k]*sW2[k*8+h];
        m2[h] = sigmoidf(v);
    }
    float* hp = H2 + (size_t)i * 8;
#pragma unroll
    for (int h = 0; h < 8; ++h) atomicAdd(hp + h, m2[h]);
}

__global__ void k_out(const int* __restrict__ src, const int* __restrict__ dst,
                      const float* __restrict__ H2, const float* __restrict__ x,
                      const float* __restrict__ W_e, const float* __restrict__ b_e,
                      float* __restrict__ out, int n_edges) {
    __shared__ float sW[22]; __shared__ float sb;
    if (threadIdx.x < 22) sW[threadIdx.x] = W_e[threadIdx.x];
    if (threadIdx.x == 0) sb = b_e[0];
    __syncthreads();
    int e = blockIdx.x * blockDim.x + threadIdx.x;
    if (e >= n_edges) return;
    int j = src[e], i = dst[e];
    const float4* hj = (const float4*)(H2 + (size_t)j * 8);
    const float4* hi = (const float4*)(H2 + (size_t)i * 8);
    float4 a0=hj[0],a1=hj[1],c0=hi[0],c1=hi[1];
    float acc = sb;
    acc += a0.x*sW[0]+a0.y*sW[1]+a0.z*sW[2]+a0.w*sW[3];
    acc += a1.x*sW[4]+a1.y*sW[5]+a1.z*sW[6]+a1.w*sW[7];
    acc += x[3*(size_t)j]*sW[8]+x[3*(size_t)j+1]*sW[9]+x[3*(size_t)j+2]*sW[10];
    acc += c0.x*sW[11]+c0.y*sW[12]+c0.z*sW[13]+c0.w*sW[14];
    acc += c1.x*sW[15]+c1.y*sW[16]+c1.z*sW[17]+c1.w*sW[18];
    acc += x[3*(size_t)i]*sW[19]+x[3*(size_t)i+1]*sW[20]+x[3*(size_t)i+2]*sW[21];
    out[e] = sigmoidf(acc);
}

// ===========================================================================
extern "C" void kernel_launch(void* const* d_in, const int* in_sizes, int n_in,
                              void* d_out, int out_size, void* d_ws, size_t ws_size,
                              hipStream_t stream) {
    const float* x    = (const float*)d_in[0];
    const int*   ei   = (const int*)d_in[1];
    const float* W_in = (const float*)d_in[2];
    const float* b_in = (const float*)d_in[3];
    const float* W1   = (const float*)d_in[4];
    const float* b1   = (const float*)d_in[5];
    const float* W2   = (const float*)d_in[6];
    const float* b2   = (const float*)d_in[7];
    const float* W_e  = (const float*)d_in[8];
    const float* b_e  = (const float*)d_in[9];

    const int n_nodes = in_sizes[0] / 3;
    const int n_edges = in_sizes[1] / 2;
    const int* src = ei;
    const int* dst = ei + n_edges;
    float* out = (float*)d_out;

    const int NB   = (n_nodes + BW - 1) >> BSH;       // buckets
    const int NBLK = (n_edges + EPB - 1) / EPB;       // partition blocks

    // workspace carve (256B aligned)
    size_t off = 0;
    auto carve = [&](size_t bytes) { size_t o = off; off += (bytes + 255) & ~(size_t)255; return o; };
    char* ws = (char*)d_ws;
    size_t o_feat   = carve((size_t)n_nodes * 12 * 4);
    size_t o_ac     = carve((size_t)n_nodes * 2 * 4);
    size_t o_hist   = carve((size_t)NBLK * NB * 4);
    size_t o_totals = carve((size_t)NB * 4);
    size_t o_base   = carve(((size_t)NB + 1) * 4);
    size_t o_sorted = carve((size_t)n_edges * 4);
    bool fast = (off <= ws_size) && (NB <= MAXNB);

    if (fast) {
        float* feat   = (float*)(ws + o_feat);
        float* ac     = (float*)(ws + o_ac);
        int*   hist   = (int*)(ws + o_hist);
        int*   totals = (int*)(ws + o_totals);
        int*   base   = (int*)(ws + o_base);
        int*   sorted = (int*)(ws + o_sorted);

        k_feat     <<<(n_nodes + TPB - 1) / TPB, TPB, 0, stream>>>(x, W_in, b_in, feat, n_nodes);
        k_hist2    <<<NBLK, TPB, 0, stream>>>(dst, hist, n_edges, NB);
        k_scan_cols<<<NB, TPB, 0, stream>>>(hist, totals, NB, NBLK);
        k_base     <<<1, MAXNB, 0, stream>>>(totals, base, NB, n_edges);
        k_scatter  <<<NBLK, TPB, 0, stream>>>(src, dst, hist, base, sorted, n_edges, NB);
        k_bucket   <<<NB, TPB, 0, stream>>>(sorted, base, feat, W1, b1, W2, b2, W_e, ac, n_nodes);
        k_out2     <<<(n_edges + TPB - 1) / TPB, TPB, 0, stream>>>(src, dst, ac, b_e, out, n_edges);
    } else {
        float* feat = (float*)d_ws;
        float* H2   = feat + (size_t)n_nodes * 12;
        k_nodes<<<(n_nodes + TPB - 1) / TPB, TPB, 0, stream>>>(x, W_in, b_in, feat, H2, n_nodes);
        k_edges<<<(n_edges + TPB - 1) / TPB, TPB, 0, stream>>>(src, dst, feat, W1, b1, W2, b2, H2, n_edges);
        k_out  <<<(n_edges + TPB - 1) / TPB, TPB, 0, stream>>>(src, dst, H2, x, W_e, b_e, out, n_edges);
    }
}

// Round 4
// 151.863 us; speedup vs baseline: 9.0432x; 1.5190x over previous
//
#include <hip/hip_runtime.h>

#define TPB     256
#define BSH     7              // bucket = dst >> 7  (128 nodes / bucket)
#define BW      128
#define EPB     4096           // edges per partition block (256 thr x 16)
#define MAXNB   1024
#define S_SPLIT 4              // edge-slices per bucket in k_bucket

static __device__ __forceinline__ float sigmoidf(float v) {
    return __builtin_amdgcn_rcpf(1.0f + __expf(-v));
}

// ===========================================================================
// K1: per-node precompute.
//   f = [tanh(x@W_in+b_in), x]  (11)
//   gi[n] = f @ (W1[0:11] - W1[11:22]) + b1   (8)   -- dst-side layer-1 term
//   gj[n] = f @ W1[11:22]                      (8)   -- src-side layer-1 term
// feat array is no longer needed anywhere.
// ===========================================================================
__global__ void k_feat(const float* __restrict__ x,
                       const float* __restrict__ W_in,
                       const float* __restrict__ b_in,
                       const float* __restrict__ W1,
                       const float* __restrict__ b1,
                       float* __restrict__ gi,
                       float* __restrict__ gj, int n_nodes) {
    __shared__ float sW1[176], sb1v[8], sWin[24], sbin[8];
    int t = threadIdx.x;
    for (int i = t; i < 176; i += blockDim.x) sW1[i] = W1[i];
    if (t < 24) sWin[t] = W_in[t];
    if (t < 8) { sb1v[t] = b1[t]; sbin[t] = b_in[t]; }
    __syncthreads();
    int n = blockIdx.x * blockDim.x + t;
    if (n >= n_nodes) return;
    float x0 = x[3*n], x1 = x[3*n+1], x2 = x[3*n+2];
    float f[11];
#pragma unroll
    for (int c = 0; c < 8; ++c)
        f[c] = tanhf(sbin[c] + x0*sWin[c] + x1*sWin[8+c] + x2*sWin[16+c]);
    f[8] = x0; f[9] = x1; f[10] = x2;
    float giv[8], gjv[8];
#pragma unroll
    for (int h = 0; h < 8; ++h) {
        float vi = sb1v[h], vj = 0.0f;
#pragma unroll
        for (int k = 0; k < 11; ++k) {
            float wa = sW1[k*8+h], wb = sW1[(11+k)*8+h];
            vi += f[k] * (wa - wb);
            vj += f[k] * wb;
        }
        giv[h] = vi; gjv[h] = vj;
    }
    float4* gip = (float4*)(gi + (size_t)n * 8);
    gip[0] = make_float4(giv[0], giv[1], giv[2], giv[3]);
    gip[1] = make_float4(giv[4], giv[5], giv[6], giv[7]);
    float4* gjp = (float4*)(gj + (size_t)n * 8);
    gjp[0] = make_float4(gjv[0], gjv[1], gjv[2], gjv[3]);
    gjp[1] = make_float4(gjv[4], gjv[5], gjv[6], gjv[7]);
}

// ===========================================================================
// K2: per-block bucket histogram (LDS only)
// ===========================================================================
__global__ void k_hist2(const int* __restrict__ dst, int* __restrict__ hist,
                        int n_edges, int NB) {
    __shared__ int cnt[MAXNB];
    for (int b = threadIdx.x; b < NB; b += blockDim.x) cnt[b] = 0;
    __syncthreads();
    int e0 = blockIdx.x * EPB;
#pragma unroll
    for (int k = 0; k < EPB / TPB; ++k) {
        int e = e0 + k * TPB + threadIdx.x;
        if (e < n_edges) atomicAdd(&cnt[dst[e] >> BSH], 1);
    }
    __syncthreads();
    for (int b = threadIdx.x; b < NB; b += blockDim.x)
        hist[(size_t)blockIdx.x * NB + b] = cnt[b];
}

// ===========================================================================
// K3: per-bucket (column) exclusive scan over blocks
// ===========================================================================
__global__ void k_scan_cols(int* __restrict__ hist, int* __restrict__ totals,
                            int NB, int NBLK) {
    __shared__ int s[TPB];
    int b = blockIdx.x, t = threadIdx.x;
    int carry = 0;
    for (int q = 0; q < NBLK; q += TPB) {
        int blk = q + t;
        int v = (blk < NBLK) ? hist[(size_t)blk * NB + b] : 0;
        __syncthreads();
        s[t] = v; __syncthreads();
        for (int o = 1; o < TPB; o <<= 1) {
            int u = (t >= o) ? s[t - o] : 0;
            __syncthreads();
            s[t] += u;
            __syncthreads();
        }
        int incl = s[t];
        int tot  = s[TPB - 1];
        if (blk < NBLK) hist[(size_t)blk * NB + b] = carry + incl - v;
        carry += tot;
    }
    if (t == 0) totals[b] = carry;
}

// K3b: exclusive scan of totals -> base
__global__ void k_base(const int* __restrict__ totals, int* __restrict__ base,
                       int NB, int n_edges) {
    __shared__ int s[MAXNB];
    int t = threadIdx.x;
    int v = (t < NB) ? totals[t] : 0;
    s[t] = v; __syncthreads();
    for (int o = 1; o < MAXNB; o <<= 1) {
        int u = (t >= o) ? s[t - o] : 0;
        __syncthreads();
        s[t] += u;
        __syncthreads();
    }
    if (t < NB) base[t] = s[t] - v;
    if (t == 0) base[NB] = n_edges;
}

// ===========================================================================
// K4: scatter pass — packed (src<<7 | dst&127)
// ===========================================================================
__global__ void k_scatter(const int* __restrict__ src, const int* __restrict__ dst,
                          const int* __restrict__ hist, const int* __restrict__ base,
                          int* __restrict__ sorted, int n_edges, int NB) {
    __shared__ int offl[MAXNB];
    for (int b = threadIdx.x; b < NB; b += blockDim.x)
        offl[b] = base[b] + hist[(size_t)blockIdx.x * NB + b];
    __syncthreads();
    int e0 = blockIdx.x * EPB;
#pragma unroll
    for (int k = 0; k < EPB / TPB; ++k) {
        int e = e0 + k * TPB + threadIdx.x;
        if (e < n_edges) {
            int d = dst[e];
            int b = d >> BSH;
            int pos = atomicAdd(&offl[b], 1);
            sorted[pos] = (src[e] << BSH) | (d & (BW - 1));
        }
    }
}

// ===========================================================================
// K5: fused per-bucket-slice MLP + reduction.
//   grid = NB * S_SPLIT; WG (b,s) handles slice s of bucket b's edges.
//   Per edge: m[h]=sig(sgi[dl][h]+gj_src[h]); m2=sig(m@W2+b2); pa,pc proj;
//   LDS atomic accumulate; partials written non-atomically to part[wg][256].
//   Software-pipelined gather of gj one iteration ahead.
// ===========================================================================
__launch_bounds__(TPB)
__global__ void k_bucket(const int* __restrict__ sorted, const int* __restrict__ base,
                         const float* __restrict__ gi, const float* __restrict__ gj,
                         const float* __restrict__ W2, const float* __restrict__ b2,
                         const float* __restrict__ W_e,
                         float* __restrict__ part, int n_nodes) {
    __shared__ float sgi[BW * 8];
    __shared__ float sa[BW], sc[BW];
    __shared__ float sW2[64], sb2[8], sWea[8], sWec[8];
    int t = threadIdx.x;
    int b = blockIdx.x >> 2;          // / S_SPLIT
    int sl = blockIdx.x & (S_SPLIT - 1);

    int nb0 = b * BW;
    int nn = min(BW, n_nodes - nb0);
    for (int i = t; i < nn * 8; i += TPB) sgi[i] = gi[(size_t)nb0 * 8 + i];
    if (t < 64) sW2[t] = W2[t];
    if (t < 8) { sb2[t] = b2[t]; sWea[t] = W_e[t]; sWec[t] = W_e[11 + t]; }
    if (t < BW) { sa[t] = 0.0f; sc[t] = 0.0f; }
    __syncthreads();

    int beg = base[b], end = base[b + 1], len = end - beg;
    int s0 = beg + (int)(((long long)len * sl) / S_SPLIT);
    int s1 = beg + (int)(((long long)len * (sl + 1)) / S_SPLIT);

    int e = s0 + t;
    bool valid = e < s1;
    int p = 0; float4 ga = make_float4(0,0,0,0), gb = ga;
    if (valid) {
        p = sorted[e];
        const float4* gp = (const float4*)(gj + ((size_t)(p >> BSH)) * 8);
        ga = gp[0]; gb = gp[1];
    }
    while (valid) {
        // prefetch next iteration
        int e2 = e + TPB;
        bool v2 = e2 < s1;
        int p2 = p; float4 ga2 = ga, gb2 = gb;
        if (v2) {
            p2 = sorted[e2];
            const float4* gp = (const float4*)(gj + ((size_t)(p2 >> BSH)) * 8);
            ga2 = gp[0]; gb2 = gp[1];
        }
        // compute current
        int dl = p & (BW - 1);
        const float* gr = &sgi[dl * 8];
        float m[8];
        m[0] = sigmoidf(gr[0] + ga.x); m[1] = sigmoidf(gr[1] + ga.y);
        m[2] = sigmoidf(gr[2] + ga.z); m[3] = sigmoidf(gr[3] + ga.w);
        m[4] = sigmoidf(gr[4] + gb.x); m[5] = sigmoidf(gr[5] + gb.y);
        m[6] = sigmoidf(gr[6] + gb.z); m[7] = sigmoidf(gr[7] + gb.w);
        float pa = 0.0f, pc = 0.0f;
#pragma unroll
        for (int h = 0; h < 8; ++h) {
            float v = sb2[h];
#pragma unroll
            for (int k = 0; k < 8; ++k) v += m[k] * sW2[k * 8 + h];
            float mm = sigmoidf(v);
            pa += mm * sWea[h];
            pc += mm * sWec[h];
        }
        atomicAdd(&sa[dl], pa);
        atomicAdd(&sc[dl], pc);
        // advance
        p = p2; ga = ga2; gb = gb2; e = e2; valid = v2;
    }
    __syncthreads();
    float val = (t < BW) ? sa[t] : sc[t - BW];
    part[(size_t)blockIdx.x * (2 * BW) + t] = val;
}

// ===========================================================================
// K6: reduce S_SPLIT partials + x-projection -> ac[2n], ac[2n+1]
// ===========================================================================
__global__ void k_acc(const float* __restrict__ part, const float* __restrict__ x,
                      const float* __restrict__ W_e, float* __restrict__ ac,
                      int n_nodes) {
    int n = blockIdx.x * blockDim.x + threadIdx.x;
    if (n >= n_nodes) return;
    int b = n >> BSH, r = n & (BW - 1);
    float a = 0.0f, c = 0.0f;
#pragma unroll
    for (int s = 0; s < S_SPLIT; ++s) {
        const float* pp = part + ((size_t)(b * S_SPLIT + s)) * (2 * BW);
        a += pp[r];
        c += pp[BW + r];
    }
    float x0 = x[3*n], x1 = x[3*n+1], x2 = x[3*n+2];
    a += x0 * W_e[8]  + x1 * W_e[9]  + x2 * W_e[10];
    c += x0 * W_e[19] + x1 * W_e[20] + x2 * W_e[21];
    ac[2*n]     = a;
    ac[2*n + 1] = c;
}

// ===========================================================================
// K7: out[e] = sigmoid(a[src] + c[dst] + b_e)
// ===========================================================================
__global__ void k_out2(const int* __restrict__ src, const int* __restrict__ dst,
                       const float* __restrict__ ac, const float* __restrict__ b_e,
                       float* __restrict__ out, int n_edges) {
    int e = blockIdx.x * blockDim.x + threadIdx.x;
    if (e >= n_edges) return;
    out[e] = sigmoidf(ac[2 * src[e]] + ac[2 * dst[e] + 1] + b_e[0]);
}

// ===========================================================================
// FALLBACK (round-1, proven) — only if NB > MAXNB or ws too small.
// ===========================================================================
__global__ void k_nodes(const float* __restrict__ x, const float* __restrict__ W_in,
                        const float* __restrict__ b_in, float* __restrict__ feat,
                        float* __restrict__ H2, int n_nodes) {
    int i = blockIdx.x * blockDim.x + threadIdx.x;
    if (i >= n_nodes) return;
    float x0 = x[3*i], x1 = x[3*i+1], x2 = x[3*i+2];
    float h[8];
#pragma unroll
    for (int c = 0; c < 8; ++c)
        h[c] = tanhf(b_in[c] + x0*W_in[c] + x1*W_in[8+c] + x2*W_in[16+c]);
    float4* fp = (float4*)(feat + (size_t)i * 12);
    fp[0] = make_float4(h[0],h[1],h[2],h[3]);
    fp[1] = make_float4(h[4],h[5],h[6],h[7]);
    fp[2] = make_float4(x0,x1,x2,0.0f);
    float4* hp = (float4*)(H2 + (size_t)i * 8);
    hp[0] = make_float4(0,0,0,0); hp[1] = make_float4(0,0,0,0);
}

__global__ void k_edges(const int* __restrict__ src, const int* __restrict__ dst,
                        const float* __restrict__ feat, const float* __restrict__ W1,
                        const float* __restrict__ b1, const float* __restrict__ W2,
                        const float* __restrict__ b2, float* __restrict__ H2,
                        int n_edges) {
    __shared__ float sW1[176], sW2[64], sb1[8], sb2[8];
    for (int t = threadIdx.x; t < 176; t += blockDim.x) sW1[t] = W1[t];
    for (int t = threadIdx.x; t < 64;  t += blockDim.x) sW2[t] = W2[t];
    if (threadIdx.x < 8) { sb1[threadIdx.x]=b1[threadIdx.x]; sb2[threadIdx.x]=b2[threadIdx.x]; }
    __syncthreads();
    int e = blockIdx.x * blockDim.x + threadIdx.x;
    if (e >= n_edges) return;
    int j = src[e], i = dst[e];
    const float4* fi = (const float4*)(feat + (size_t)i * 12);
    const float4* fj = (const float4*)(feat + (size_t)j * 12);
    float4 i0=fi[0],i1=fi[1],i2=fi[2],j0=fj[0],j1=fj[1],j2=fj[2];
    float xi[11]={i0.x,i0.y,i0.z,i0.w,i1.x,i1.y,i1.z,i1.w,i2.x,i2.y,i2.z};
    float xj[11]={j0.x,j0.y,j0.z,j0.w,j1.x,j1.y,j1.z,j1.w,j2.x,j2.y,j2.z};
    float dd[11];
#pragma unroll
    for (int k = 0; k < 11; ++k) dd[k]=xj[k]-xi[k];
    float m[8];
#pragma unroll
    for (int h = 0; h < 8; ++h) {
        float v = sb1[h];
#pragma unroll
        for (int k = 0; k < 11; ++k) v += xi[k]*sW1[k*8+h];
#pragma unroll
        for (int k = 0; k < 11; ++k) v += dd[k]*sW1[(11+k)*8+h];
        m[h] = sigmoidf(v);
    }
    float m2[8];
#pragma unroll
    for (int h = 0; h < 8; ++h) {
        float v = sb2[h];
#pragma unroll
        for (int k = 0; k < 8; ++k) v += m[k]*sW2[k*8+h];
        m2[h] = sigmoidf(v);
    }
    float* hp = H2 + (size_t)i * 8;
#pragma unroll
    for (int h = 0; h < 8; ++h) atomicAdd(hp + h, m2[h]);
}

__global__ void k_out(const int* __restrict__ src, const int* __restrict__ dst,
                      const float* __restrict__ H2, const float* __restrict__ x,
                      const float* __restrict__ W_e, const float* __restrict__ b_e,
                      float* __restrict__ out, int n_edges) {
    __shared__ float sW[22]; __shared__ float sb;
    if (threadIdx.x < 22) sW[threadIdx.x] = W_e[threadIdx.x];
    if (threadIdx.x == 0) sb = b_e[0];
    __syncthreads();
    int e = blockIdx.x * blockDim.x + threadIdx.x;
    if (e >= n_edges) return;
    int j = src[e], i = dst[e];
    const float4* hj = (const float4*)(H2 + (size_t)j * 8);
    const float4* hi = (const float4*)(H2 + (size_t)i * 8);
    float4 a0=hj[0],a1=hj[1],c0=hi[0],c1=hi[1];
    float acc = sb;
    acc += a0.x*sW[0]+a0.y*sW[1]+a0.z*sW[2]+a0.w*sW[3];
    acc += a1.x*sW[4]+a1.y*sW[5]+a1.z*sW[6]+a1.w*sW[7];
    acc += x[3*(size_t)j]*sW[8]+x[3*(size_t)j+1]*sW[9]+x[3*(size_t)j+2]*sW[10];
    acc += c0.x*sW[11]+c0.y*sW[12]+c0.z*sW[13]+c0.w*sW[14];
    acc += c1.x*sW[15]+c1.y*sW[16]+c1.z*sW[17]+c1.w*sW[18];
    acc += x[3*(size_t)i]*sW[19]+x[3*(size_t)i+1]*sW[20]+x[3*(size_t)i+2]*sW[21];
    out[e] = sigmoidf(acc);
}

// ===========================================================================
extern "C" void kernel_launch(void* const* d_in, const int* in_sizes, int n_in,
                              void* d_out, int out_size, void* d_ws, size_t ws_size,
                              hipStream_t stream) {
    const float* x    = (const float*)d_in[0];
    const int*   ei   = (const int*)d_in[1];
    const float* W_in = (const float*)d_in[2];
    const float* b_in = (const float*)d_in[3];
    const float* W1   = (const float*)d_in[4];
    const float* b1   = (const float*)d_in[5];
    const float* W2   = (const float*)d_in[6];
    const float* b2   = (const float*)d_in[7];
    const float* W_e  = (const float*)d_in[8];
    const float* b_e  = (const float*)d_in[9];

    const int n_nodes = in_sizes[0] / 3;
    const int n_edges = in_sizes[1] / 2;
    const int* src = ei;
    const int* dst = ei + n_edges;
    float* out = (float*)d_out;

    const int NB   = (n_nodes + BW - 1) >> BSH;
    const int NBLK = (n_edges + EPB - 1) / EPB;

    size_t off = 0;
    auto carve = [&](size_t bytes) { size_t o = off; off += (bytes + 255) & ~(size_t)255; return o; };
    char* ws = (char*)d_ws;
    size_t o_gi     = carve((size_t)n_nodes * 8 * 4);
    size_t o_gj     = carve((size_t)n_nodes * 8 * 4);
    size_t o_ac     = carve((size_t)n_nodes * 2 * 4);
    size_t o_hist   = carve((size_t)NBLK * NB * 4);
    size_t o_totals = carve((size_t)NB * 4);
    size_t o_base   = carve(((size_t)NB + 1) * 4);
    size_t o_sorted = carve((size_t)n_edges * 4);
    size_t o_part   = carve((size_t)NB * S_SPLIT * 2 * BW * 4);
    bool fast = (off <= ws_size) && (NB <= MAXNB);

    if (fast) {
        float* gi     = (float*)(ws + o_gi);
        float* gj     = (float*)(ws + o_gj);
        float* ac     = (float*)(ws + o_ac);
        int*   hist   = (int*)(ws + o_hist);
        int*   totals = (int*)(ws + o_totals);
        int*   base   = (int*)(ws + o_base);
        int*   sorted = (int*)(ws + o_sorted);
        float* part   = (float*)(ws + o_part);

        k_feat     <<<(n_nodes + TPB - 1) / TPB, TPB, 0, stream>>>(x, W_in, b_in, W1, b1, gi, gj, n_nodes);
        k_hist2    <<<NBLK, TPB, 0, stream>>>(dst, hist, n_edges, NB);
        k_scan_cols<<<NB, TPB, 0, stream>>>(hist, totals, NB, NBLK);
        k_base     <<<1, MAXNB, 0, stream>>>(totals, base, NB, n_edges);
        k_scatter  <<<NBLK, TPB, 0, stream>>>(src, dst, hist, base, sorted, n_edges, NB);
        k_bucket   <<<NB * S_SPLIT, TPB, 0, stream>>>(sorted, base, gi, gj, W2, b2, W_e, part, n_nodes);
        k_acc      <<<(n_nodes + TPB - 1) / TPB, TPB, 0, stream>>>(part, x, W_e, ac, n_nodes);
        k_out2     <<<(n_edges + TPB - 1) / TPB, TPB, 0, stream>>>(src, dst, ac, b_e, out, n_edges);
    } else {
        float* feat = (float*)d_ws;
        float* H2   = feat + (size_t)n_nodes * 12;
        k_nodes<<<(n_nodes + TPB - 1) / TPB, TPB, 0, stream>>>(x, W_in, b_in, feat, H2, n_nodes);
        k_edges<<<(n_edges + TPB - 1) / TPB, TPB, 0, stream>>>(src, dst, feat, W1, b1, W2, b2, H2, n_edges);
        k_out  <<<(n_edges + TPB - 1) / TPB, TPB, 0, stream>>>(src, dst, H2, x, W_e, b_e, out, n_edges);
    }
}

// Round 5
// 130.881 us; speedup vs baseline: 10.4930x; 1.1603x over previous
//
#include <hip/hip_runtime.h>

#define TPB     256
#define BSH     7              // bucket = dst >> 7  (128 nodes / bucket)
#define BW      128
#define EPB     16384          // edges per partition block (256 thr x 16 x int4)
#define MAXNB   1024
#define S_SPLIT 4              // edge-slices per bucket in k_bucket

static __device__ __forceinline__ float sigmoidf(float v) {
    return __builtin_amdgcn_rcpf(1.0f + __expf(-v));
}

// ===========================================================================
// K1: per-node precompute.
//   f = [tanh(x@W_in+b_in), x]  (11)
//   gi[n] = f @ (W1[0:11] - W1[11:22]) + b1   (8)   -- dst-side layer-1 term
//   gj[n] = f @ W1[11:22]                      (8)   -- src-side layer-1 term
// ===========================================================================
__global__ void k_feat(const float* __restrict__ x,
                       const float* __restrict__ W_in,
                       const float* __restrict__ b_in,
                       const float* __restrict__ W1,
                       const float* __restrict__ b1,
                       float* __restrict__ gi,
                       float* __restrict__ gj, int n_nodes) {
    __shared__ float sW1[176], sb1v[8], sWin[24], sbin[8];
    int t = threadIdx.x;
    for (int i = t; i < 176; i += blockDim.x) sW1[i] = W1[i];
    if (t < 24) sWin[t] = W_in[t];
    if (t < 8) { sb1v[t] = b1[t]; sbin[t] = b_in[t]; }
    __syncthreads();
    int n = blockIdx.x * blockDim.x + t;
    if (n >= n_nodes) return;
    float x0 = x[3*n], x1 = x[3*n+1], x2 = x[3*n+2];
    float f[11];
#pragma unroll
    for (int c = 0; c < 8; ++c)
        f[c] = tanhf(sbin[c] + x0*sWin[c] + x1*sWin[8+c] + x2*sWin[16+c]);
    f[8] = x0; f[9] = x1; f[10] = x2;
    float giv[8], gjv[8];
#pragma unroll
    for (int h = 0; h < 8; ++h) {
        float vi = sb1v[h], vj = 0.0f;
#pragma unroll
        for (int k = 0; k < 11; ++k) {
            float wa = sW1[k*8+h], wb = sW1[(11+k)*8+h];
            vi += f[k] * (wa - wb);
            vj += f[k] * wb;
        }
        giv[h] = vi; gjv[h] = vj;
    }
    float4* gip = (float4*)(gi + (size_t)n * 8);
    gip[0] = make_float4(giv[0], giv[1], giv[2], giv[3]);
    gip[1] = make_float4(giv[4], giv[5], giv[6], giv[7]);
    float4* gjp = (float4*)(gj + (size_t)n * 8);
    gjp[0] = make_float4(gjv[0], gjv[1], gjv[2], gjv[3]);
    gjp[1] = make_float4(gjv[4], gjv[5], gjv[6], gjv[7]);
}

// ===========================================================================
// K2: per-block bucket histogram (LDS only), int4 streaming loads
// ===========================================================================
__global__ void k_hist2(const int* __restrict__ dst, int* __restrict__ hist,
                        int n_edges, int NB) {
    __shared__ int cnt[MAXNB];
    for (int b = threadIdx.x; b < NB; b += blockDim.x) cnt[b] = 0;
    __syncthreads();
    int e0 = blockIdx.x * EPB + threadIdx.x * 4;
#pragma unroll
    for (int k = 0; k < EPB / (TPB * 4); ++k) {
        int e = e0 + k * TPB * 4;
        if (e + 3 < n_edges) {
            int4 d4 = *(const int4*)(dst + e);
            atomicAdd(&cnt[d4.x >> BSH], 1);
            atomicAdd(&cnt[d4.y >> BSH], 1);
            atomicAdd(&cnt[d4.z >> BSH], 1);
            atomicAdd(&cnt[d4.w >> BSH], 1);
        } else {
            int lim = n_edges - e; // may be <=0
            for (int q = 0; q < 4 && q < lim; ++q)
                atomicAdd(&cnt[dst[e + q] >> BSH], 1);
        }
    }
    __syncthreads();
    for (int b = threadIdx.x; b < NB; b += blockDim.x)
        hist[(size_t)blockIdx.x * NB + b] = cnt[b];
}

// ===========================================================================
// K3: per-bucket (column) exclusive scan over blocks (NBLK <= 256 now)
// ===========================================================================
__global__ void k_scan_cols(int* __restrict__ hist, int* __restrict__ totals,
                            int NB, int NBLK) {
    __shared__ int s[TPB];
    int b = blockIdx.x, t = threadIdx.x;
    int carry = 0;
    for (int q = 0; q < NBLK; q += TPB) {
        int blk = q + t;
        int v = (blk < NBLK) ? hist[(size_t)blk * NB + b] : 0;
        __syncthreads();
        s[t] = v; __syncthreads();
        for (int o = 1; o < TPB; o <<= 1) {
            int u = (t >= o) ? s[t - o] : 0;
            __syncthreads();
            s[t] += u;
            __syncthreads();
        }
        int incl = s[t];
        int tot  = s[TPB - 1];
        if (blk < NBLK) hist[(size_t)blk * NB + b] = carry + incl - v;
        carry += tot;
    }
    if (t == 0) totals[b] = carry;
}

// K3b: exclusive scan of totals -> base
__global__ void k_base(const int* __restrict__ totals, int* __restrict__ base,
                       int NB, int n_edges) {
    __shared__ int s[MAXNB];
    int t = threadIdx.x;
    int v = (t < NB) ? totals[t] : 0;
    s[t] = v; __syncthreads();
    for (int o = 1; o < MAXNB; o <<= 1) {
        int u = (t >= o) ? s[t - o] : 0;
        __syncthreads();
        s[t] += u;
        __syncthreads();
    }
    if (t < NB) base[t] = s[t] - v;
    if (t == 0) base[NB] = n_edges;
}

// ===========================================================================
// K4: scatter pass — packed (src<<7 | dst&127), int4 streaming loads.
// EPB=16384 -> ~21 entries (84B) contiguous per bucket per block.
// ===========================================================================
__global__ void k_scatter(const int* __restrict__ src, const int* __restrict__ dst,
                          const int* __restrict__ hist, const int* __restrict__ base,
                          int* __restrict__ sorted, int n_edges, int NB) {
    __shared__ int offl[MAXNB];
    for (int b = threadIdx.x; b < NB; b += blockDim.x)
        offl[b] = base[b] + hist[(size_t)blockIdx.x * NB + b];
    __syncthreads();
    int e0 = blockIdx.x * EPB + threadIdx.x * 4;
#pragma unroll
    for (int k = 0; k < EPB / (TPB * 4); ++k) {
        int e = e0 + k * TPB * 4;
        if (e + 3 < n_edges) {
            int4 s4 = *(const int4*)(src + e);
            int4 d4 = *(const int4*)(dst + e);
            int p, b;
            b = d4.x >> BSH; p = atomicAdd(&offl[b], 1); sorted[p] = (s4.x << BSH) | (d4.x & (BW-1));
            b = d4.y >> BSH; p = atomicAdd(&offl[b], 1); sorted[p] = (s4.y << BSH) | (d4.y & (BW-1));
            b = d4.z >> BSH; p = atomicAdd(&offl[b], 1); sorted[p] = (s4.z << BSH) | (d4.z & (BW-1));
            b = d4.w >> BSH; p = atomicAdd(&offl[b], 1); sorted[p] = (s4.w << BSH) | (d4.w & (BW-1));
        } else {
            int lim = n_edges - e;
            for (int q = 0; q < 4 && q < lim; ++q) {
                int d = dst[e + q];
                int b = d >> BSH;
                int p = atomicAdd(&offl[b], 1);
                sorted[p] = (src[e + q] << BSH) | (d & (BW - 1));
            }
        }
    }
}

// ===========================================================================
// K5: fused per-bucket-slice MLP + reduction (unchanged structure).
// ===========================================================================
__launch_bounds__(TPB)
__global__ void k_bucket(const int* __restrict__ sorted, const int* __restrict__ base,
                         const float* __restrict__ gi, const float* __restrict__ gj,
                         const float* __restrict__ W2, const float* __restrict__ b2,
                         const float* __restrict__ W_e,
                         float* __restrict__ part, int n_nodes) {
    __shared__ float sgi[BW * 8];
    __shared__ float sa[BW], sc[BW];
    __shared__ float sW2[64], sb2[8], sWea[8], sWec[8];
    int t = threadIdx.x;
    int b = blockIdx.x >> 2;          // / S_SPLIT
    int sl = blockIdx.x & (S_SPLIT - 1);

    int nb0 = b * BW;
    int nn = min(BW, n_nodes - nb0);
    for (int i = t; i < nn * 8; i += TPB) sgi[i] = gi[(size_t)nb0 * 8 + i];
    if (t < 64) sW2[t] = W2[t];
    if (t < 8) { sb2[t] = b2[t]; sWea[t] = W_e[t]; sWec[t] = W_e[11 + t]; }
    if (t < BW) { sa[t] = 0.0f; sc[t] = 0.0f; }
    __syncthreads();

    int beg = base[b], end = base[b + 1], len = end - beg;
    int s0 = beg + (int)(((long long)len * sl) / S_SPLIT);
    int s1 = beg + (int)(((long long)len * (sl + 1)) / S_SPLIT);

    int e = s0 + t;
    bool valid = e < s1;
    int p = 0; float4 ga = make_float4(0,0,0,0), gb = ga;
    if (valid) {
        p = sorted[e];
        const float4* gp = (const float4*)(gj + ((size_t)(p >> BSH)) * 8);
        ga = gp[0]; gb = gp[1];
    }
    while (valid) {
        int e2 = e + TPB;
        bool v2 = e2 < s1;
        int p2 = p; float4 ga2 = ga, gb2 = gb;
        if (v2) {
            p2 = sorted[e2];
            const float4* gp = (const float4*)(gj + ((size_t)(p2 >> BSH)) * 8);
            ga2 = gp[0]; gb2 = gp[1];
        }
        int dl = p & (BW - 1);
        const float* gr = &sgi[dl * 8];
        float m[8];
        m[0] = sigmoidf(gr[0] + ga.x); m[1] = sigmoidf(gr[1] + ga.y);
        m[2] = sigmoidf(gr[2] + ga.z); m[3] = sigmoidf(gr[3] + ga.w);
        m[4] = sigmoidf(gr[4] + gb.x); m[5] = sigmoidf(gr[5] + gb.y);
        m[6] = sigmoidf(gr[6] + gb.z); m[7] = sigmoidf(gr[7] + gb.w);
        float pa = 0.0f, pc = 0.0f;
#pragma unroll
        for (int h = 0; h < 8; ++h) {
            float v = sb2[h];
#pragma unroll
            for (int k = 0; k < 8; ++k) v += m[k] * sW2[k * 8 + h];
            float mm = sigmoidf(v);
            pa += mm * sWea[h];
            pc += mm * sWec[h];
        }
        atomicAdd(&sa[dl], pa);
        atomicAdd(&sc[dl], pc);
        p = p2; ga = ga2; gb = gb2; e = e2; valid = v2;
    }
    __syncthreads();
    float val = (t < BW) ? sa[t] : sc[t - BW];
    part[(size_t)blockIdx.x * (2 * BW) + t] = val;
}

// ===========================================================================
// K6: reduce S_SPLIT partials + x-projection -> ac[2n], ac[2n+1]
// ===========================================================================
__global__ void k_acc(const float* __restrict__ part, const float* __restrict__ x,
                      const float* __restrict__ W_e, float* __restrict__ ac,
                      int n_nodes) {
    int n = blockIdx.x * blockDim.x + threadIdx.x;
    if (n >= n_nodes) return;
    int b = n >> BSH, r = n & (BW - 1);
    float a = 0.0f, c = 0.0f;
#pragma unroll
    for (int s = 0; s < S_SPLIT; ++s) {
        const float* pp = part + ((size_t)(b * S_SPLIT + s)) * (2 * BW);
        a += pp[r];
        c += pp[BW + r];
    }
    float x0 = x[3*n], x1 = x[3*n+1], x2 = x[3*n+2];
    a += x0 * W_e[8]  + x1 * W_e[9]  + x2 * W_e[10];
    c += x0 * W_e[19] + x1 * W_e[20] + x2 * W_e[21];
    ac[2*n]     = a;
    ac[2*n + 1] = c;
}

// ===========================================================================
// K7: out[e] = sigmoid(a[src] + c[dst] + b_e), 4 edges/thread
// ===========================================================================
__global__ void k_out2(const int* __restrict__ src, const int* __restrict__ dst,
                       const float* __restrict__ ac, const float* __restrict__ b_e,
                       float* __restrict__ out, int n_edges) {
    float bb = b_e[0];
    int e = (blockIdx.x * blockDim.x + threadIdx.x) * 4;
    if (e + 3 < n_edges) {
        int4 s4 = *(const int4*)(src + e);
        int4 d4 = *(const int4*)(dst + e);
        float4 o;
        o.x = sigmoidf(ac[2*s4.x] + ac[2*d4.x + 1] + bb);
        o.y = sigmoidf(ac[2*s4.y] + ac[2*d4.y + 1] + bb);
        o.z = sigmoidf(ac[2*s4.z] + ac[2*d4.z + 1] + bb);
        o.w = sigmoidf(ac[2*s4.w] + ac[2*d4.w + 1] + bb);
        *(float4*)(out + e) = o;
    } else {
        for (int q = e; q < n_edges; ++q)
            out[q] = sigmoidf(ac[2*src[q]] + ac[2*dst[q] + 1] + bb);
    }
}

// ===========================================================================
// FALLBACK (round-1, proven) — only if NB > MAXNB or ws too small.
// ===========================================================================
__global__ void k_nodes(const float* __restrict__ x, const float* __restrict__ W_in,
                        const float* __restrict__ b_in, float* __restrict__ feat,
                        float* __restrict__ H2, int n_nodes) {
    int i = blockIdx.x * blockDim.x + threadIdx.x;
    if (i >= n_nodes) return;
    float x0 = x[3*i], x1 = x[3*i+1], x2 = x[3*i+2];
    float h[8];
#pragma unroll
    for (int c = 0; c < 8; ++c)
        h[c] = tanhf(b_in[c] + x0*W_in[c] + x1*W_in[8+c] + x2*W_in[16+c]);
    float4* fp = (float4*)(feat + (size_t)i * 12);
    fp[0] = make_float4(h[0],h[1],h[2],h[3]);
    fp[1] = make_float4(h[4],h[5],h[6],h[7]);
    fp[2] = make_float4(x0,x1,x2,0.0f);
    float4* hp = (float4*)(H2 + (size_t)i * 8);
    hp[0] = make_float4(0,0,0,0); hp[1] = make_float4(0,0,0,0);
}

__global__ void k_edges(const int* __restrict__ src, const int* __restrict__ dst,
                        const float* __restrict__ feat, const float* __restrict__ W1,
                        const float* __restrict__ b1, const float* __restrict__ W2,
                        const float* __restrict__ b2, float* __restrict__ H2,
                        int n_edges) {
    __shared__ float sW1[176], sW2[64], sb1[8], sb2[8];
    for (int t = threadIdx.x; t < 176; t += blockDim.x) sW1[t] = W1[t];
    for (int t = threadIdx.x; t < 64;  t += blockDim.x) sW2[t] = W2[t];
    if (threadIdx.x < 8) { sb1[threadIdx.x]=b1[threadIdx.x]; sb2[threadIdx.x]=b2[threadIdx.x]; }
    __syncthreads();
    int e = blockIdx.x * blockDim.x + threadIdx.x;
    if (e >= n_edges) return;
    int j = src[e], i = dst[e];
    const float4* fi = (const float4*)(feat + (size_t)i * 12);
    const float4* fj = (const float4*)(feat + (size_t)j * 12);
    float4 i0=fi[0],i1=fi[1],i2=fi[2],j0=fj[0],j1=fj[1],j2=fj[2];
    float xi[11]={i0.x,i0.y,i0.z,i0.w,i1.x,i1.y,i1.z,i1.w,i2.x,i2.y,i2.z};
    float xj[11]={j0.x,j0.y,j0.z,j0.w,j1.x,j1.y,j1.z,j1.w,j2.x,j2.y,j2.z};
    float dd[11];
#pragma unroll
    for (int k = 0; k < 11; ++k) dd[k]=xj[k]-xi[k];
    float m[8];
#pragma unroll
    for (int h = 0; h < 8; ++h) {
        float v = sb1[h];
#pragma unroll
        for (int k = 0; k < 11; ++k) v += xi[k]*sW1[k*8+h];
#pragma unroll
        for (int k = 0; k < 11; ++k) v += dd[k]*sW1[(11+k)*8+h];
        m[h] = sigmoidf(v);
    }
    float m2[8];
#pragma unroll
    for (int h = 0; h < 8; ++h) {
        float v = sb2[h];
#pragma unroll
        for (int k = 0; k < 8; ++k) v += m[k]*sW2[k*8+h];
        m2[h] = sigmoidf(v);
    }
    float* hp = H2 + (size_t)i * 8;
#pragma unroll
    for (int h = 0; h < 8; ++h) atomicAdd(hp + h, m2[h]);
}

__global__ void k_out(const int* __restrict__ src, const int* __restrict__ dst,
                      const float* __restrict__ H2, const float* __restrict__ x,
                      const float* __restrict__ W_e, const float* __restrict__ b_e,
                      float* __restrict__ out, int n_edges) {
    __shared__ float sW[22]; __shared__ float sb;
    if (threadIdx.x < 22) sW[threadIdx.x] = W_e[threadIdx.x];
    if (threadIdx.x == 0) sb = b_e[0];
    __syncthreads();
    int e = blockIdx.x * blockDim.x + threadIdx.x;
    if (e >= n_edges) return;
    int j = src[e], i = dst[e];
    const float4* hj = (const float4*)(H2 + (size_t)j * 8);
    const float4* hi = (const float4*)(H2 + (size_t)i * 8);
    float4 a0=hj[0],a1=hj[1],c0=hi[0],c1=hi[1];
    float acc = sb;
    acc += a0.x*sW[0]+a0.y*sW[1]+a0.z*sW[2]+a0.w*sW[3];
    acc += a1.x*sW[4]+a1.y*sW[5]+a1.z*sW[6]+a1.w*sW[7];
    acc += x[3*(size_t)j]*sW[8]+x[3*(size_t)j+1]*sW[9]+x[3*(size_t)j+2]*sW[10];
    acc += c0.x*sW[11]+c0.y*sW[12]+c0.z*sW[13]+c0.w*sW[14];
    acc += c1.x*sW[15]+c1.y*sW[16]+c1.z*sW[17]+c1.w*sW[18];
    acc += x[3*(size_t)i]*sW[19]+x[3*(size_t)i+1]*sW[20]+x[3*(size_t)i+2]*sW[21];
    out[e] = sigmoidf(acc);
}

// ===========================================================================
extern "C" void kernel_launch(void* const* d_in, const int* in_sizes, int n_in,
                              void* d_out, int out_size, void* d_ws, size_t ws_size,
                              hipStream_t stream) {
    const float* x    = (const float*)d_in[0];
    const int*   ei   = (const int*)d_in[1];
    const float* W_in = (const float*)d_in[2];
    const float* b_in = (const float*)d_in[3];
    const float* W1   = (const float*)d_in[4];
    const float* b1   = (const float*)d_in[5];
    const float* W2   = (const float*)d_in[6];
    const float* b2   = (const float*)d_in[7];
    const float* W_e  = (const float*)d_in[8];
    const float* b_e  = (const float*)d_in[9];

    const int n_nodes = in_sizes[0] / 3;
    const int n_edges = in_sizes[1] / 2;
    const int* src = ei;
    const int* dst = ei + n_edges;
    float* out = (float*)d_out;

    const int NB   = (n_nodes + BW - 1) >> BSH;
    const int NBLK = (n_edges + EPB - 1) / EPB;

    size_t off = 0;
    auto carve = [&](size_t bytes) { size_t o = off; off += (bytes + 255) & ~(size_t)255; return o; };
    char* ws = (char*)d_ws;
    size_t o_gi     = carve((size_t)n_nodes * 8 * 4);
    size_t o_gj     = carve((size_t)n_nodes * 8 * 4);
    size_t o_ac     = carve((size_t)n_nodes * 2 * 4);
    size_t o_hist   = carve((size_t)NBLK * NB * 4);
    size_t o_totals = carve((size_t)NB * 4);
    size_t o_base   = carve(((size_t)NB + 1) * 4);
    size_t o_sorted = carve((size_t)n_edges * 4);
    size_t o_part   = carve((size_t)NB * S_SPLIT * 2 * BW * 4);
    bool fast = (off <= ws_size) && (NB <= MAXNB);

    if (fast) {
        float* gi     = (float*)(ws + o_gi);
        float* gj     = (float*)(ws + o_gj);
        float* ac     = (float*)(ws + o_ac);
        int*   hist   = (int*)(ws + o_hist);
        int*   totals = (int*)(ws + o_totals);
        int*   base   = (int*)(ws + o_base);
        int*   sorted = (int*)(ws + o_sorted);
        float* part   = (float*)(ws + o_part);

        k_feat     <<<(n_nodes + TPB - 1) / TPB, TPB, 0, stream>>>(x, W_in, b_in, W1, b1, gi, gj, n_nodes);
        k_hist2    <<<NBLK, TPB, 0, stream>>>(dst, hist, n_edges, NB);
        k_scan_cols<<<NB, TPB, 0, stream>>>(hist, totals, NB, NBLK);
        k_base     <<<1, MAXNB, 0, stream>>>(totals, base, NB, n_edges);
        k_scatter  <<<NBLK, TPB, 0, stream>>>(src, dst, hist, base, sorted, n_edges, NB);
        k_bucket   <<<NB * S_SPLIT, TPB, 0, stream>>>(sorted, base, gi, gj, W2, b2, W_e, part, n_nodes);
        k_acc      <<<(n_nodes + TPB - 1) / TPB, TPB, 0, stream>>>(part, x, W_e, ac, n_nodes);
        k_out2     <<<(n_edges / 4 + TPB - 1) / TPB + 1, TPB, 0, stream>>>(src, dst, ac, b_e, out, n_edges);
    } else {
        float* feat = (float*)d_ws;
        float* H2   = feat + (size_t)n_nodes * 12;
        k_nodes<<<(n_nodes + TPB - 1) / TPB, TPB, 0, stream>>>(x, W_in, b_in, feat, H2, n_nodes);
        k_edges<<<(n_edges + TPB - 1) / TPB, TPB, 0, stream>>>(src, dst, feat, W1, b1, W2, b2, H2, n_edges);
        k_out  <<<(n_edges + TPB - 1) / TPB, TPB, 0, stream>>>(src, dst, H2, x, W_e, b_e, out, n_edges);
    }
}